// Round 1
// baseline (339.825 us; speedup 1.0000x reference)
//
#include <hip/hip_runtime.h>
#include <hip/hip_bf16.h>

#define B_TOK 16384
#define TOPK 2
#define NEXP 64
#define HID 512
#define FFN 1024
#define NASSIGN (B_TOK * TOPK)   // 32768
#define CAP (NASSIGN / NEXP)     // 512 assignments per expert (balanced)

typedef unsigned short u16;
typedef __bf16 bf16_t;
typedef bf16_t bf16x8 __attribute__((ext_vector_type(8)));
typedef float f32x4 __attribute__((ext_vector_type(4)));

__device__ __forceinline__ u16 f2bf(float f) {
  union { float f; unsigned u; } v; v.f = f;
  unsigned r = v.u + 0x7fffu + ((v.u >> 16) & 1u);  // round-to-nearest-even
  return (u16)(r >> 16);
}

// ---------------------------------------------------------------- routing
__global__ void k_route(const int* __restrict__ ids, int* __restrict__ cnt,
                        int* __restrict__ tok_of, int* __restrict__ slot_pos) {
  int n = blockIdx.x * blockDim.x + threadIdx.x;
  if (n >= NASSIGN) return;
  int e = ids[n];
  int r = atomicAdd(&cnt[e], 1);
  int p = e * CAP + r;
  tok_of[p] = n >> 1;       // token index for sorted slot p
  slot_pos[n] = p;          // inverse map: assignment n -> sorted slot
}

// ------------------------------------------------- gather + fp32->bf16 cast
__global__ void k_gather(const float* __restrict__ hs, const int* __restrict__ tok_of,
                         u16* __restrict__ Xg) {
  int p = blockIdx.x;
  int t = threadIdx.x;  // 256 threads, 2 elems each
  const float2 v = reinterpret_cast<const float2*>(hs + (size_t)tok_of[p] * HID)[t];
  unsigned pack = (unsigned)f2bf(v.x) | ((unsigned)f2bf(v.y) << 16);
  reinterpret_cast<unsigned*>(Xg + (size_t)p * HID)[t] = pack;
}

// --------------------------------- per-expert transpose + fp32->bf16 cast
// in: [E][R][C] fp32 ; out: [E][C][R] bf16
template <int R, int C>
__global__ void k_transpose_bf16(const float* __restrict__ in, u16* __restrict__ out) {
  __shared__ float tile[32][33];  // +1 pad: conflict-free transpose
  int e = blockIdx.z;
  int c0 = blockIdx.x * 32;
  int r0 = blockIdx.y * 32;
  const float* src = in + (size_t)e * R * C;
  u16* dst = out + (size_t)e * R * C;
  int tx = threadIdx.x & 31, ty = threadIdx.x >> 5;  // ty 0..7
#pragma unroll
  for (int p = 0; p < 4; p++) {
    int r = p * 8 + ty;
    tile[r][tx] = src[(size_t)(r0 + r) * C + (c0 + tx)];
  }
  __syncthreads();
#pragma unroll
  for (int p = 0; p < 4; p++) {
    int rO = p * 8 + ty;  // out row within tile (= original col)
    dst[(size_t)(c0 + rO) * R + (r0 + tx)] = f2bf(tile[tx][rO]);
  }
}

// ------------------------------------------------------------ grouped GEMM
// C[e*CAP+m][n] = sum_k A[e*CAP+m][k] * Bw[e][n][k]   (Bw stored n-major, k-contig)
// 128x128 tile, BK=32, 4 waves (2x2), mfma_f32_16x16x32_bf16, 4x4 frags/wave.
template <int K, int NN, bool SILU>
__global__ __launch_bounds__(256) void k_gemm(const u16* __restrict__ A,
                                              const u16* __restrict__ Bw,
                                              void* __restrict__ Cout) {
  constexpr int MT = CAP / 128;  // 4
  constexpr int NT = NN / 128;
  int wg = blockIdx.x;
  int e = wg / (MT * NT);
  int rm = wg % (MT * NT);
  int mt = rm / NT, nt = rm % NT;

  const u16* Ab = A + ((size_t)e * CAP + (size_t)mt * 128) * K;
  const u16* Bb = Bw + (size_t)e * NN * K + (size_t)nt * 128 * K;

  __shared__ __align__(16) u16 As[128 * 32];
  __shared__ __align__(16) u16 Bs[128 * 32];

  int t = threadIdx.x;
  int kc = t & 3, rr = t >> 2;          // staging: 16B chunk, row 0..63 (+64)
  int lane = t & 63, wv = t >> 6;
  int wm = wv >> 1, wn = wv & 1;        // 2x2 wave grid, 64x64 each
  int l15 = lane & 15, lhi = lane >> 4;

  f32x4 acc[4][4];
#pragma unroll
  for (int i = 0; i < 4; i++)
#pragma unroll
    for (int j = 0; j < 4; j++) {
      f32x4 z = {0.f, 0.f, 0.f, 0.f};
      acc[i][j] = z;
    }

  for (int kk = 0; kk < K; kk += 32) {
    const u16* ga = Ab + (size_t)rr * K + kk + kc * 8;
    const u16* gb = Bb + (size_t)rr * K + kk + kc * 8;
    bf16x8 a0 = *reinterpret_cast<const bf16x8*>(ga);
    bf16x8 a1 = *reinterpret_cast<const bf16x8*>(ga + (size_t)64 * K);
    bf16x8 b0 = *reinterpret_cast<const bf16x8*>(gb);
    bf16x8 b1 = *reinterpret_cast<const bf16x8*>(gb + (size_t)64 * K);
    __syncthreads();  // previous iter done reading LDS
    *reinterpret_cast<bf16x8*>(&As[rr * 32 + kc * 8]) = a0;
    *reinterpret_cast<bf16x8*>(&As[(rr + 64) * 32 + kc * 8]) = a1;
    *reinterpret_cast<bf16x8*>(&Bs[rr * 32 + kc * 8]) = b0;
    *reinterpret_cast<bf16x8*>(&Bs[(rr + 64) * 32 + kc * 8]) = b1;
    __syncthreads();

    bf16x8 af[4], bfr[4];
#pragma unroll
    for (int mf = 0; mf < 4; mf++)
      af[mf] = *reinterpret_cast<const bf16x8*>(&As[(wm * 64 + mf * 16 + l15) * 32 + lhi * 8]);
#pragma unroll
    for (int nf = 0; nf < 4; nf++)
      bfr[nf] = *reinterpret_cast<const bf16x8*>(&Bs[(wn * 64 + nf * 16 + l15) * 32 + lhi * 8]);
#pragma unroll
    for (int mf = 0; mf < 4; mf++)
#pragma unroll
      for (int nf = 0; nf < 4; nf++)
        acc[mf][nf] = __builtin_amdgcn_mfma_f32_16x16x32_bf16(af[mf], bfr[nf], acc[mf][nf], 0, 0, 0);
  }

  // epilogue: D row = lhi*4+reg, col = l15 (verified C/D layout)
#pragma unroll
  for (int mf = 0; mf < 4; mf++) {
#pragma unroll
    for (int nf = 0; nf < 4; nf++) {
#pragma unroll
      for (int rg = 0; rg < 4; rg++) {
        float v = acc[mf][nf][rg];
        int grow = mt * 128 + wm * 64 + mf * 16 + lhi * 4 + rg;
        int gcol = nt * 128 + wn * 64 + nf * 16 + l15;
        size_t off = ((size_t)e * CAP + grow) * NN + gcol;
        if constexpr (SILU) {
          v = v / (1.0f + __expf(-v));  // silu
          ((u16*)Cout)[off] = f2bf(v);
        } else {
          ((float*)Cout)[off] = v;
        }
      }
    }
  }
}

// ------------------------------------------- weighted combine (no atomics)
__global__ void k_combine(const float* __restrict__ yws, const int* __restrict__ slot_pos,
                          const float* __restrict__ w, float* __restrict__ out) {
  int tk = blockIdx.x;
  int t = threadIdx.x;  // 256 threads, float2 each
  int p0 = slot_pos[2 * tk], p1 = slot_pos[2 * tk + 1];
  float w0 = w[2 * tk], w1 = w[2 * tk + 1];
  float2 a = reinterpret_cast<const float2*>(yws + (size_t)p0 * HID)[t];
  float2 b = reinterpret_cast<const float2*>(yws + (size_t)p1 * HID)[t];
  float2 o;
  o.x = w0 * a.x + w1 * b.x;
  o.y = w0 * a.y + w1 * b.y;
  reinterpret_cast<float2*>(out + (size_t)tk * HID)[t] = o;
}

// ---------------------------------------------------------------- launcher
extern "C" void kernel_launch(void* const* d_in, const int* in_sizes, int n_in,
                              void* d_out, int out_size, void* d_ws, size_t ws_size,
                              hipStream_t stream) {
  const float* hs = (const float*)d_in[0];
  const float* wts = (const float*)d_in[1];
  const int* ids = (const int*)d_in[2];
  const float* W1 = (const float*)d_in[3];
  const float* W2 = (const float*)d_in[4];
  float* out = (float*)d_out;

  char* ws = (char*)d_ws;
  size_t o = 0;
  int* cnt = (int*)(ws + o);       o += 1024;
  int* slot_pos = (int*)(ws + o);  o += (size_t)NASSIGN * 4;
  int* tok_of = (int*)(ws + o);    o += (size_t)NASSIGN * 4;
  o = (o + 255) & ~(size_t)255;
  u16* Xg = (u16*)(ws + o);        o += (size_t)NASSIGN * HID * 2;      // 32 MB
  u16* hid = (u16*)(ws + o);       o += (size_t)NASSIGN * FFN * 2;      // 64 MB
  u16* W1T = (u16*)(ws + o);       o += (size_t)NEXP * HID * FFN * 2;   // 64 MB
  u16* W2T = (u16*)(ws + o);       o += (size_t)NEXP * HID * FFN * 2;   // 64 MB
  float* yws = (float*)W1T;  // overlay: W1T dead after gemm1; yws is 64 MB fp32

  hipMemsetAsync(cnt, 0, NEXP * sizeof(int), stream);
  k_route<<<(NASSIGN + 255) / 256, 256, 0, stream>>>(ids, cnt, tok_of, slot_pos);
  k_gather<<<NASSIGN, 256, 0, stream>>>(hs, tok_of, Xg);
  k_transpose_bf16<HID, FFN><<<dim3(FFN / 32, HID / 32, NEXP), 256, 0, stream>>>(W1, W1T);
  k_transpose_bf16<FFN, HID><<<dim3(HID / 32, FFN / 32, NEXP), 256, 0, stream>>>(W2, W2T);
  k_gemm<HID, FFN, true><<<NEXP * (CAP / 128) * (FFN / 128), 256, 0, stream>>>(Xg, W1T, hid);
  k_gemm<FFN, HID, false><<<NEXP * (CAP / 128) * (HID / 128), 256, 0, stream>>>(hid, W2T, yws);
  k_combine<<<B_TOK, 256, 0, stream>>>(yws, slot_pos, wts, out);
}

// Round 2
// 321.859 us; speedup vs baseline: 1.0558x; 1.0558x over previous
//
#include <hip/hip_runtime.h>
#include <hip/hip_bf16.h>

#define B_TOK 16384
#define TOPK 2
#define NEXP 64
#define HID 512
#define FFN 1024
#define NASSIGN (B_TOK * TOPK)   // 32768
#define CAP (NASSIGN / NEXP)     // 512 assignments per expert (balanced)

typedef unsigned short u16;
typedef __bf16 bf16_t;
typedef bf16_t bf16x8 __attribute__((ext_vector_type(8)));
typedef float f32x4 __attribute__((ext_vector_type(4)));

__device__ __forceinline__ u16 f2bf(float f) {
  union { float f; unsigned u; } v; v.f = f;
  unsigned r = v.u + 0x7fffu + ((v.u >> 16) & 1u);  // round-to-nearest-even
  return (u16)(r >> 16);
}

#define GLOAD_LDS16(g, l)                                                     \
  __builtin_amdgcn_global_load_lds((const __attribute__((address_space(1))) void*)(g), \
                                   (__attribute__((address_space(3))) void*)(l), 16, 0, 0)

// ---------------------------------------------------------------- routing
__global__ void k_route(const int* __restrict__ ids, int* __restrict__ cnt,
                        int* __restrict__ tok_of, int* __restrict__ slot_pos) {
  int n = blockIdx.x * blockDim.x + threadIdx.x;
  if (n >= NASSIGN) return;
  int e = ids[n];
  int r = atomicAdd(&cnt[e], 1);
  int p = e * CAP + r;
  tok_of[p] = n >> 1;       // token index for sorted slot p
  slot_pos[n] = p;          // inverse map: assignment n -> sorted slot
}

// ------------------------------------------------- gather + fp32->bf16 cast
__global__ void k_gather(const float* __restrict__ hs, const int* __restrict__ tok_of,
                         u16* __restrict__ Xg) {
  int p = blockIdx.x;
  int t = threadIdx.x;  // 256 threads, 2 elems each
  const float2 v = reinterpret_cast<const float2*>(hs + (size_t)tok_of[p] * HID)[t];
  unsigned pack = (unsigned)f2bf(v.x) | ((unsigned)f2bf(v.y) << 16);
  reinterpret_cast<unsigned*>(Xg + (size_t)p * HID)[t] = pack;
}

// --------------------------------- per-expert transpose + fp32->bf16 cast
// in: [E][R][C] fp32 ; out: [E][C][R] bf16
template <int R, int C>
__global__ void k_transpose_bf16(const float* __restrict__ in, u16* __restrict__ out) {
  __shared__ float tile[32][33];  // +1 pad: conflict-free transpose
  int e = blockIdx.z;
  int c0 = blockIdx.x * 32;
  int r0 = blockIdx.y * 32;
  const float* src = in + (size_t)e * R * C;
  u16* dst = out + (size_t)e * R * C;
  int tx = threadIdx.x & 31, ty = threadIdx.x >> 5;  // ty 0..7
#pragma unroll
  for (int p = 0; p < 4; p++) {
    int r = p * 8 + ty;
    tile[r][tx] = src[(size_t)(r0 + r) * C + (c0 + tx)];
  }
  __syncthreads();
#pragma unroll
  for (int p = 0; p < 4; p++) {
    int rO = p * 8 + ty;  // out row within tile (= original col)
    dst[(size_t)(c0 + rO) * R + (r0 + tx)] = f2bf(tile[tx][rO]);
  }
}

// ------------------------------------------------------------ grouped GEMM
// C[e*CAP+m][n] = sum_k A[e*CAP+m][k] * Bw[e][n][k]   (Bw n-major, k-contig)
// 128x128 tile, BK=64, 4 waves (2x2), mfma_f32_16x16x32_bf16, 4x4 frags/wave.
// Staging: global_load_lds dwordx4, linear LDS dest; XOR swizzle applied to the
// per-lane GLOBAL source chunk and to the ds_read address (rule #21): LDS
// position (row, p) holds logical 16B-chunk p ^ (row&7).
template <int K, int NN, bool SILU>
__global__ __launch_bounds__(256) void k_gemm(const u16* __restrict__ A,
                                              const u16* __restrict__ Bw,
                                              void* __restrict__ Cout) {
  constexpr int MT = CAP / 128;        // 4
  constexpr int NT = NN / 128;
  constexpr int NWG = NEXP * MT * NT;  // %8 == 0
  constexpr int Q = NWG / 8;
  // XCD chunked swizzle: XCD x gets logical blocks [x*Q, (x+1)*Q)
  int wg = (blockIdx.x % 8) * Q + blockIdx.x / 8;
  int e = wg / (MT * NT);
  int rm = wg % (MT * NT);
  int mt = rm / NT, nt = rm % NT;

  const u16* Ab = A + ((size_t)e * CAP + (size_t)mt * 128) * K;
  const u16* Bb = Bw + (size_t)e * NN * K + (size_t)nt * 128 * K;

  __shared__ __align__(16) u16 As[128 * 64];   // 16 KB
  __shared__ __align__(16) u16 Bs[128 * 64];   // 16 KB

  int t = threadIdx.x;
  int lane = t & 63, wv = t >> 6;
  int wm = wv >> 1, wn = wv & 1;        // 2x2 wave grid, 64x64 each
  int l15 = lane & 15, lhi = lane >> 4;

  // staging geometry: call i covers rows [i*32, i*32+32), thread t -> row
  // i*32 + t/8, LDS chunk position p = t%8, global chunk g = p ^ (row&7)
  int srow = t >> 3;                    // 0..31
  int gchunk = (t & 7) ^ (srow & 7);
  const u16* gA0 = Ab + (size_t)srow * K + gchunk * 8;
  const u16* gB0 = Bb + (size_t)srow * K + gchunk * 8;
  char* ldsA0 = (char*)As + wv * 1024;  // per-wave uniform base; HW adds lane*16
  char* ldsB0 = (char*)Bs + wv * 1024;

  f32x4 acc[4][4];
#pragma unroll
  for (int i = 0; i < 4; i++)
#pragma unroll
    for (int j = 0; j < 4; j++) {
      f32x4 z = {0.f, 0.f, 0.f, 0.f};
      acc[i][j] = z;
    }

  for (int kk = 0; kk < K; kk += 64) {
#pragma unroll
    for (int i = 0; i < 4; i++) {
      GLOAD_LDS16(gA0 + (size_t)i * 32 * K + kk, ldsA0 + i * 4096);
      GLOAD_LDS16(gB0 + (size_t)i * 32 * K + kk, ldsB0 + i * 4096);
    }
    __syncthreads();  // drains vmcnt -> tile visible to all waves

#pragma unroll
    for (int kks = 0; kks < 2; kks++) {
      bf16x8 af[4], bfr[4];
#pragma unroll
      for (int mf = 0; mf < 4; mf++) {
        int row = wm * 64 + mf * 16 + l15;
        int c = (kks * 4 + lhi) ^ (row & 7);
        af[mf] = *reinterpret_cast<const bf16x8*>(&As[row * 64 + c * 8]);
      }
#pragma unroll
      for (int nf = 0; nf < 4; nf++) {
        int row = wn * 64 + nf * 16 + l15;
        int c = (kks * 4 + lhi) ^ (row & 7);
        bfr[nf] = *reinterpret_cast<const bf16x8*>(&Bs[row * 64 + c * 8]);
      }
#pragma unroll
      for (int mf = 0; mf < 4; mf++)
#pragma unroll
        for (int nf = 0; nf < 4; nf++)
          acc[mf][nf] = __builtin_amdgcn_mfma_f32_16x16x32_bf16(af[mf], bfr[nf], acc[mf][nf], 0, 0, 0);
    }
    __syncthreads();  // all waves done reading before next stage overwrites
  }

  // epilogue: D row = lhi*4+reg, col = l15 (verified C/D layout)
#pragma unroll
  for (int mf = 0; mf < 4; mf++) {
#pragma unroll
    for (int nf = 0; nf < 4; nf++) {
#pragma unroll
      for (int rg = 0; rg < 4; rg++) {
        float v = acc[mf][nf][rg];
        int grow = mt * 128 + wm * 64 + mf * 16 + lhi * 4 + rg;
        int gcol = nt * 128 + wn * 64 + nf * 16 + l15;
        size_t off = ((size_t)e * CAP + grow) * NN + gcol;
        if constexpr (SILU) {
          v = v / (1.0f + __expf(-v));  // silu
          ((u16*)Cout)[off] = f2bf(v);
        } else {
          ((float*)Cout)[off] = v;
        }
      }
    }
  }
}

// ------------------------------------------- weighted combine (no atomics)
__global__ void k_combine(const float* __restrict__ yws, const int* __restrict__ slot_pos,
                          const float* __restrict__ w, float* __restrict__ out) {
  int tk = blockIdx.x;
  int t = threadIdx.x;  // 256 threads, float2 each
  int p0 = slot_pos[2 * tk], p1 = slot_pos[2 * tk + 1];
  float w0 = w[2 * tk], w1 = w[2 * tk + 1];
  float2 a = reinterpret_cast<const float2*>(yws + (size_t)p0 * HID)[t];
  float2 b = reinterpret_cast<const float2*>(yws + (size_t)p1 * HID)[t];
  float2 o;
  o.x = w0 * a.x + w1 * b.x;
  o.y = w0 * a.y + w1 * b.y;
  reinterpret_cast<float2*>(out + (size_t)tk * HID)[t] = o;
}

// ---------------------------------------------------------------- launcher
extern "C" void kernel_launch(void* const* d_in, const int* in_sizes, int n_in,
                              void* d_out, int out_size, void* d_ws, size_t ws_size,
                              hipStream_t stream) {
  const float* hs = (const float*)d_in[0];
  const float* wts = (const float*)d_in[1];
  const int* ids = (const int*)d_in[2];
  const float* W1 = (const float*)d_in[3];
  const float* W2 = (const float*)d_in[4];
  float* out = (float*)d_out;

  char* ws = (char*)d_ws;
  size_t o = 0;
  int* cnt = (int*)(ws + o);       o += 1024;
  int* slot_pos = (int*)(ws + o);  o += (size_t)NASSIGN * 4;
  int* tok_of = (int*)(ws + o);    o += (size_t)NASSIGN * 4;
  o = (o + 255) & ~(size_t)255;
  u16* Xg = (u16*)(ws + o);        o += (size_t)NASSIGN * HID * 2;      // 32 MB
  u16* hid = (u16*)(ws + o);       o += (size_t)NASSIGN * FFN * 2;      // 64 MB
  u16* W1T = (u16*)(ws + o);       o += (size_t)NEXP * HID * FFN * 2;   // 64 MB
  u16* W2T = (u16*)(ws + o);       o += (size_t)NEXP * HID * FFN * 2;   // 64 MB
  float* yws = (float*)W1T;  // overlay: W1T dead after gemm1; yws is 64 MB fp32

  hipMemsetAsync(cnt, 0, NEXP * sizeof(int), stream);
  k_route<<<(NASSIGN + 255) / 256, 256, 0, stream>>>(ids, cnt, tok_of, slot_pos);
  k_gather<<<NASSIGN, 256, 0, stream>>>(hs, tok_of, Xg);
  k_transpose_bf16<HID, FFN><<<dim3(FFN / 32, HID / 32, NEXP), 256, 0, stream>>>(W1, W1T);
  k_transpose_bf16<FFN, HID><<<dim3(HID / 32, FFN / 32, NEXP), 256, 0, stream>>>(W2, W2T);
  k_gemm<HID, FFN, true><<<NEXP * (CAP / 128) * (FFN / 128), 256, 0, stream>>>(Xg, W1T, hid);
  k_gemm<FFN, HID, false><<<NEXP * (CAP / 128) * (HID / 128), 256, 0, stream>>>(hid, W2T, yws);
  k_combine<<<B_TOK, 256, 0, stream>>>(yws, slot_pos, wts, out);
}

// Round 3
// 304.493 us; speedup vs baseline: 1.1160x; 1.0570x over previous
//
#include <hip/hip_runtime.h>
#include <hip/hip_bf16.h>

#define B_TOK 16384
#define TOPK 2
#define NEXP 64
#define HID 512
#define FFN 1024
#define NASSIGN (B_TOK * TOPK)   // 32768
#define CAP (NASSIGN / NEXP)     // 512 assignments per expert (balanced)

typedef unsigned short u16;
typedef __bf16 bf16_t;
typedef bf16_t bf16x8 __attribute__((ext_vector_type(8)));
typedef float f32x4 __attribute__((ext_vector_type(4)));

__device__ __forceinline__ u16 f2bf(float f) {
  union { float f; unsigned u; } v; v.f = f;
  unsigned r = v.u + 0x7fffu + ((v.u >> 16) & 1u);  // round-to-nearest-even
  return (u16)(r >> 16);
}

#define GLOAD_LDS16(g, l)                                                     \
  __builtin_amdgcn_global_load_lds((const __attribute__((address_space(1))) void*)(g), \
                                   (__attribute__((address_space(3))) void*)(l), 16, 0, 0)

// ---------------------------------------------------------------- routing
__global__ void k_route(const int* __restrict__ ids, int* __restrict__ cnt,
                        int* __restrict__ tok_of, int* __restrict__ slot_pos) {
  int n = blockIdx.x * blockDim.x + threadIdx.x;
  if (n >= NASSIGN) return;
  int e = ids[n];
  int r = atomicAdd(&cnt[e], 1);
  int p = e * CAP + r;
  tok_of[p] = n >> 1;       // token index for sorted slot p
  slot_pos[n] = p;          // inverse map: assignment n -> sorted slot
}

// ------------------------------------------------- gather + fp32->bf16 cast
// one wave per sorted slot row; float4 loads, uint2 (4xbf16) stores
__global__ void k_gather(const float* __restrict__ hs, const int* __restrict__ tok_of,
                         u16* __restrict__ Xg) {
  int p = blockIdx.x * 4 + (threadIdx.x >> 6);
  int lane = threadIdx.x & 63;
  const float4* src = reinterpret_cast<const float4*>(hs + (size_t)tok_of[p] * HID);
  uint2* dst = reinterpret_cast<uint2*>(Xg + (size_t)p * HID);
#pragma unroll
  for (int i = 0; i < 2; i++) {
    float4 v = src[i * 64 + lane];
    uint2 o;
    o.x = (unsigned)f2bf(v.x) | ((unsigned)f2bf(v.y) << 16);
    o.y = (unsigned)f2bf(v.z) | ((unsigned)f2bf(v.w) << 16);
    dst[i * 64 + lane] = o;
  }
}

// --------------------------------- per-expert transpose + fp32->bf16 cast
// in: [E][R][C] fp32 ; out: [E][C][R] bf16.  64x64 tiles; writes are 32B/thread,
// 128B bursts per output row.
template <int R, int C>
__global__ void k_transpose_bf16(const float* __restrict__ in, u16* __restrict__ out) {
  __shared__ float tile[64][65];
  int e = blockIdx.z;
  int c0 = blockIdx.x * 64;
  int r0 = blockIdx.y * 64;
  const float* src = in + (size_t)e * R * C;
  u16* dst = out + (size_t)e * R * C;
  int tx = threadIdx.x & 63, ty = threadIdx.x >> 6;  // ty 0..3
#pragma unroll
  for (int p = 0; p < 16; p++) {
    int r = p * 4 + ty;
    tile[r][tx] = src[(size_t)(r0 + r) * C + (c0 + tx)];
  }
  __syncthreads();
  int rO = threadIdx.x >> 2, seg = threadIdx.x & 3;  // output row (=orig col), 16-elem segment
  unsigned pk[8];
#pragma unroll
  for (int j = 0; j < 8; j++) {
    float a = tile[seg * 16 + 2 * j][rO];
    float b = tile[seg * 16 + 2 * j + 1][rO];
    pk[j] = (unsigned)f2bf(a) | ((unsigned)f2bf(b) << 16);
  }
  uint4* dp = reinterpret_cast<uint4*>(dst + (size_t)(c0 + rO) * R + r0 + seg * 16);
  dp[0] = make_uint4(pk[0], pk[1], pk[2], pk[3]);
  dp[1] = make_uint4(pk[4], pk[5], pk[6], pk[7]);
}

// ------------------------------------------------------------ grouped GEMM
// C[e*CAP+m][n] = sum_k A[e*CAP+m][k] * Bw[e][n][k]   (Bw n-major, k-contig)
// 128x128 tile, 4 waves (2x2), mfma_f32_16x16x32_bf16, 4x4 frags/wave.
// 2-phase double-buffered pipeline at BK=32 granularity: STAGE(next) issued
// BEFORE compute(cur); __syncthreads (vmcnt0+barrier) once per half-step, so
// load flight overlaps ds_read+MFMA of the current half-tile.
// Swizzle (rule #21): LDS linear dest; logical 16B chunk c stored at phys
// c ^ ((row>>1)&3); applied to global source AND ds_read address.
template <int K, int NN, bool SILU>
__global__ __launch_bounds__(256) void k_gemm(const u16* __restrict__ A,
                                              const u16* __restrict__ Bw,
                                              void* __restrict__ Cout) {
  constexpr int MT = CAP / 128;        // 4
  constexpr int NT = NN / 128;
  constexpr int NWG = NEXP * MT * NT;  // %8 == 0
  constexpr int Q = NWG / 8;
  constexpr int NS = K / 32;           // half-steps
  int wg = (blockIdx.x % 8) * Q + blockIdx.x / 8;  // XCD chunked swizzle
  int e = wg / (MT * NT);
  int rm = wg % (MT * NT);
  int mt = rm / NT, nt = rm % NT;

  const u16* Ab = A + ((size_t)e * CAP + (size_t)mt * 128) * K;
  const u16* Bb = Bw + (size_t)e * NN * K + (size_t)nt * 128 * K;

  // 4 buffers of 8KB: A0 A1 B0 B1
  __shared__ __align__(16) char sm[32768];

  int t = threadIdx.x;
  int lane = t & 63, wv = t >> 6;
  int wm = wv >> 1, wn = wv & 1;        // 2x2 wave grid, 64x64 each
  int l15 = lane & 15, lhi = lane >> 4;

  // staging: thread t -> row (t>>2) (+64 for 2nd call), logical chunk
  // (t&3)^((t>>3)&3); LDS linear pos = t within each 4KB half
  int srow = t >> 2;
  int gchunk = (t & 3) ^ ((t >> 3) & 3);
  const u16* gA0 = Ab + (size_t)srow * K + gchunk * 8;
  const u16* gB0 = Bb + (size_t)srow * K + gchunk * 8;
  char* ldsw = sm + wv * 1024;          // per-wave uniform base; HW adds lane*16

#define STAGE(bufsel, kk)                                                   \
  do {                                                                      \
    GLOAD_LDS16(gA0 + (kk), ldsw + (bufsel)*8192);                          \
    GLOAD_LDS16(gA0 + (kk) + (size_t)64 * K, ldsw + (bufsel)*8192 + 4096);  \
    GLOAD_LDS16(gB0 + (kk), ldsw + 16384 + (bufsel)*8192);                  \
    GLOAD_LDS16(gB0 + (kk) + (size_t)64 * K, ldsw + 16384 + (bufsel)*8192 + 4096); \
  } while (0)

  f32x4 acc[4][4];
#pragma unroll
  for (int i = 0; i < 4; i++)
#pragma unroll
    for (int j = 0; j < 4; j++) {
      f32x4 z = {0.f, 0.f, 0.f, 0.f};
      acc[i][j] = z;
    }

  // fragment read offsets (bytes within a buffer): row*64 + phys_chunk*16
  int physk = lhi ^ ((l15 >> 1) & 3);
  int offA[4], offB[4];
#pragma unroll
  for (int f = 0; f < 4; f++) {
    offA[f] = (wm * 64 + f * 16 + l15) * 64 + physk * 16;
    offB[f] = (wn * 64 + f * 16 + l15) * 64 + physk * 16;
  }

  STAGE(0, 0);
  __syncthreads();

  for (int s = 0; s < NS; s++) {
    int cur = s & 1;
    if (s + 1 < NS) STAGE(cur ^ 1, (s + 1) * 32);
    const char* bA = sm + cur * 8192;
    const char* bB = sm + 16384 + cur * 8192;
    bf16x8 af[4], bfr[4];
#pragma unroll
    for (int mf = 0; mf < 4; mf++)
      af[mf] = *reinterpret_cast<const bf16x8*>(bA + offA[mf]);
#pragma unroll
    for (int nf = 0; nf < 4; nf++)
      bfr[nf] = *reinterpret_cast<const bf16x8*>(bB + offB[nf]);
#pragma unroll
    for (int mf = 0; mf < 4; mf++)
#pragma unroll
      for (int nf = 0; nf < 4; nf++)
        acc[mf][nf] = __builtin_amdgcn_mfma_f32_16x16x32_bf16(af[mf], bfr[nf], acc[mf][nf], 0, 0, 0);
    __syncthreads();  // drains this step's prefetch; all waves done reading cur
  }
#undef STAGE

  // epilogue: D row = lhi*4+reg, col = l15 (verified C/D layout)
#pragma unroll
  for (int mf = 0; mf < 4; mf++) {
#pragma unroll
    for (int nf = 0; nf < 4; nf++) {
#pragma unroll
      for (int rg = 0; rg < 4; rg++) {
        float v = acc[mf][nf][rg];
        int grow = mt * 128 + wm * 64 + mf * 16 + lhi * 4 + rg;
        int gcol = nt * 128 + wn * 64 + nf * 16 + l15;
        size_t off = ((size_t)e * CAP + grow) * NN + gcol;
        if constexpr (SILU) {
          v = v / (1.0f + __expf(-v));  // silu
          ((u16*)Cout)[off] = f2bf(v);
        } else {
          ((float*)Cout)[off] = v;
        }
      }
    }
  }
}

// ------------------------------------------- weighted combine (no atomics)
__global__ void k_combine(const float* __restrict__ yws, const int* __restrict__ slot_pos,
                          const float* __restrict__ w, float* __restrict__ out) {
  int tk = blockIdx.x;
  int t = threadIdx.x;  // 256 threads, float2 each
  int p0 = slot_pos[2 * tk], p1 = slot_pos[2 * tk + 1];
  float w0 = w[2 * tk], w1 = w[2 * tk + 1];
  float2 a = reinterpret_cast<const float2*>(yws + (size_t)p0 * HID)[t];
  float2 b = reinterpret_cast<const float2*>(yws + (size_t)p1 * HID)[t];
  float2 o;
  o.x = w0 * a.x + w1 * b.x;
  o.y = w0 * a.y + w1 * b.y;
  reinterpret_cast<float2*>(out + (size_t)tk * HID)[t] = o;
}

// ---------------------------------------------------------------- launcher
extern "C" void kernel_launch(void* const* d_in, const int* in_sizes, int n_in,
                              void* d_out, int out_size, void* d_ws, size_t ws_size,
                              hipStream_t stream) {
  const float* hs = (const float*)d_in[0];
  const float* wts = (const float*)d_in[1];
  const int* ids = (const int*)d_in[2];
  const float* W1 = (const float*)d_in[3];
  const float* W2 = (const float*)d_in[4];
  float* out = (float*)d_out;

  char* ws = (char*)d_ws;
  size_t o = 0;
  int* cnt = (int*)(ws + o);       o += 1024;
  int* slot_pos = (int*)(ws + o);  o += (size_t)NASSIGN * 4;
  int* tok_of = (int*)(ws + o);    o += (size_t)NASSIGN * 4;
  o = (o + 255) & ~(size_t)255;
  u16* Xg = (u16*)(ws + o);        o += (size_t)NASSIGN * HID * 2;      // 32 MB
  u16* hid = (u16*)(ws + o);       o += (size_t)NASSIGN * FFN * 2;      // 64 MB
  u16* W1T = (u16*)(ws + o);       o += (size_t)NEXP * HID * FFN * 2;   // 64 MB
  u16* W2T = (u16*)(ws + o);       o += (size_t)NEXP * HID * FFN * 2;   // 64 MB
  float* yws = (float*)W1T;  // overlay: W1T dead after gemm1; yws is 64 MB fp32

  hipMemsetAsync(cnt, 0, NEXP * sizeof(int), stream);
  k_route<<<(NASSIGN + 255) / 256, 256, 0, stream>>>(ids, cnt, tok_of, slot_pos);
  k_gather<<<NASSIGN / 4, 256, 0, stream>>>(hs, tok_of, Xg);
  k_transpose_bf16<HID, FFN><<<dim3(FFN / 64, HID / 64, NEXP), 256, 0, stream>>>(W1, W1T);
  k_transpose_bf16<FFN, HID><<<dim3(HID / 64, FFN / 64, NEXP), 256, 0, stream>>>(W2, W2T);
  k_gemm<HID, FFN, true><<<NEXP * (CAP / 128) * (FFN / 128), 256, 0, stream>>>(Xg, W1T, hid);
  k_gemm<FFN, HID, false><<<NEXP * (CAP / 128) * (HID / 128), 256, 0, stream>>>(hid, W2T, yws);
  k_combine<<<B_TOK, 256, 0, stream>>>(yws, slot_pos, wts, out);
}

// Round 4
// 303.013 us; speedup vs baseline: 1.1215x; 1.0049x over previous
//
#include <hip/hip_runtime.h>
#include <hip/hip_bf16.h>

#define B_TOK 16384
#define TOPK 2
#define NEXP 64
#define HID 512
#define FFN 1024
#define NASSIGN (B_TOK * TOPK)   // 32768
#define CAP (NASSIGN / NEXP)     // 512 assignments per expert (balanced)

typedef unsigned short u16;
typedef __bf16 bf16_t;
typedef bf16_t bf16x8 __attribute__((ext_vector_type(8)));
typedef float f32x4 __attribute__((ext_vector_type(4)));

__device__ __forceinline__ u16 f2bf(float f) {
  union { float f; unsigned u; } v; v.f = f;
  unsigned r = v.u + 0x7fffu + ((v.u >> 16) & 1u);  // round-to-nearest-even
  return (u16)(r >> 16);
}

#define GLOAD_LDS16(g, l)                                                     \
  __builtin_amdgcn_global_load_lds((const __attribute__((address_space(1))) void*)(g), \
                                   (__attribute__((address_space(3))) void*)(l), 16, 0, 0)

// ---------------------------------------------------------------- routing
__global__ void k_route(const int* __restrict__ ids, int* __restrict__ cnt,
                        int* __restrict__ tok_of, int* __restrict__ slot_pos) {
  int n = blockIdx.x * blockDim.x + threadIdx.x;
  if (n >= NASSIGN) return;
  int e = ids[n];
  int r = atomicAdd(&cnt[e], 1);
  int p = e * CAP + r;
  tok_of[p] = n >> 1;       // token index for sorted slot p
  slot_pos[n] = p;          // inverse map: assignment n -> sorted slot
}

// ------------------------------------------------- gather + fp32->bf16 cast
// one wave per sorted slot row; float4 loads, uint2 (4xbf16) stores
__global__ void k_gather(const float* __restrict__ hs, const int* __restrict__ tok_of,
                         u16* __restrict__ Xg) {
  int p = blockIdx.x * 4 + (threadIdx.x >> 6);
  int lane = threadIdx.x & 63;
  const float4* src = reinterpret_cast<const float4*>(hs + (size_t)tok_of[p] * HID);
  uint2* dst = reinterpret_cast<uint2*>(Xg + (size_t)p * HID);
#pragma unroll
  for (int i = 0; i < 2; i++) {
    float4 v = src[i * 64 + lane];
    uint2 o;
    o.x = (unsigned)f2bf(v.x) | ((unsigned)f2bf(v.y) << 16);
    o.y = (unsigned)f2bf(v.z) | ((unsigned)f2bf(v.w) << 16);
    dst[i * 64 + lane] = o;
  }
}

// --------------------------------- per-expert transpose + fp32->bf16 cast
// in: [E][R][C] fp32 ; out: [E][C][R] bf16.  64x64 tiles; writes are 32B/thread,
// 128B bursts per output row.
template <int R, int C>
__global__ void k_transpose_bf16(const float* __restrict__ in, u16* __restrict__ out) {
  __shared__ float tile[64][65];
  int e = blockIdx.z;
  int c0 = blockIdx.x * 64;
  int r0 = blockIdx.y * 64;
  const float* src = in + (size_t)e * R * C;
  u16* dst = out + (size_t)e * R * C;
  int tx = threadIdx.x & 63, ty = threadIdx.x >> 6;  // ty 0..3
#pragma unroll
  for (int p = 0; p < 16; p++) {
    int r = p * 4 + ty;
    tile[r][tx] = src[(size_t)(r0 + r) * C + (c0 + tx)];
  }
  __syncthreads();
  int rO = threadIdx.x >> 2, seg = threadIdx.x & 3;  // output row (=orig col), 16-elem segment
  unsigned pk[8];
#pragma unroll
  for (int j = 0; j < 8; j++) {
    float a = tile[seg * 16 + 2 * j][rO];
    float b = tile[seg * 16 + 2 * j + 1][rO];
    pk[j] = (unsigned)f2bf(a) | ((unsigned)f2bf(b) << 16);
  }
  uint4* dp = reinterpret_cast<uint4*>(dst + (size_t)(c0 + rO) * R + r0 + seg * 16);
  dp[0] = make_uint4(pk[0], pk[1], pk[2], pk[3]);
  dp[1] = make_uint4(pk[4], pk[5], pk[6], pk[7]);
}

// ------------------------------------------------------------ grouped GEMM
// C[e*CAP+m][n] = sum_k A[e*CAP+m][k] * Bw[e][n][k]   (Bw n-major, k-contig)
// 128x128 tile, 4 waves (2x2), mfma_f32_16x16x32_bf16, 4x4 frags/wave.
// Depth-2 counted-vmcnt pipeline (T4): per BK=32 step:
//   ds_read frags -> lgkmcnt(0) -> barrier (cur free) -> STAGE(cur, s+2)
//   -> 16 MFMA -> vmcnt(4) (older 4 loads only; newest 4 stay in flight)
//   -> barrier.  vmcnt never drains to 0 in the main loop.
// Swizzle (rule #21): LDS linear dest; logical 16B chunk c stored at phys
// c ^ ((row>>1)&3); applied to global source AND ds_read address.
template <int K, int NN, bool SILU>
__global__ __launch_bounds__(256) void k_gemm(const u16* __restrict__ A,
                                              const u16* __restrict__ Bw,
                                              void* __restrict__ Cout) {
  constexpr int MT = CAP / 128;        // 4
  constexpr int NT = NN / 128;
  constexpr int NWG = NEXP * MT * NT;  // %8 == 0
  constexpr int Q = NWG / 8;
  constexpr int NS = K / 32;           // BK=32 steps
  int wg = (blockIdx.x % 8) * Q + blockIdx.x / 8;  // XCD chunked swizzle
  int e = wg / (MT * NT);
  int rm = wg % (MT * NT);
  int mt = rm / NT, nt = rm % NT;

  const u16* Ab = A + ((size_t)e * CAP + (size_t)mt * 128) * K;
  const u16* Bb = Bw + (size_t)e * NN * K + (size_t)nt * 128 * K;

  // 4 buffers of 8KB: A0 A1 B0 B1
  __shared__ __align__(16) char sm[32768];

  int t = threadIdx.x;
  int lane = t & 63, wv = t >> 6;
  int wm = wv >> 1, wn = wv & 1;        // 2x2 wave grid, 64x64 each
  int l15 = lane & 15, lhi = lane >> 4;

  // staging: thread t -> row (t>>2) (+64 for 2nd call), logical chunk
  // (t&3)^((t>>3)&3); LDS linear pos = t within each 4KB half
  int srow = t >> 2;
  int gchunk = (t & 3) ^ ((t >> 3) & 3);
  const u16* gA0 = Ab + (size_t)srow * K + gchunk * 8;
  const u16* gB0 = Bb + (size_t)srow * K + gchunk * 8;
  char* ldsw = sm + wv * 1024;          // per-wave uniform base; HW adds lane*16

#define STAGE(bufsel, kk)                                                   \
  do {                                                                      \
    GLOAD_LDS16(gA0 + (kk), ldsw + (bufsel)*8192);                          \
    GLOAD_LDS16(gA0 + (kk) + (size_t)64 * K, ldsw + (bufsel)*8192 + 4096);  \
    GLOAD_LDS16(gB0 + (kk), ldsw + 16384 + (bufsel)*8192);                  \
    GLOAD_LDS16(gB0 + (kk) + (size_t)64 * K, ldsw + 16384 + (bufsel)*8192 + 4096); \
  } while (0)

  f32x4 acc[4][4];
#pragma unroll
  for (int i = 0; i < 4; i++)
#pragma unroll
    for (int j = 0; j < 4; j++) {
      f32x4 z = {0.f, 0.f, 0.f, 0.f};
      acc[i][j] = z;
    }

  // fragment read offsets (bytes within a buffer): row*64 + phys_chunk*16
  int physk = lhi ^ ((l15 >> 1) & 3);
  int offA[4], offB[4];
#pragma unroll
  for (int f = 0; f < 4; f++) {
    offA[f] = (wm * 64 + f * 16 + l15) * 64 + physk * 16;
    offB[f] = (wn * 64 + f * 16 + l15) * 64 + physk * 16;
  }

  // prologue: fill both buffers; wait only the first (older 4 of 8)
  STAGE(0, 0);
  STAGE(1, 32);
  asm volatile("s_waitcnt vmcnt(4)" ::: "memory");
  __builtin_amdgcn_sched_barrier(0);
  __builtin_amdgcn_s_barrier();

#pragma unroll 2
  for (int s = 0; s < NS; s++) {
    int cur = s & 1;
    const char* bA = sm + cur * 8192;
    const char* bB = sm + 16384 + cur * 8192;
    bf16x8 af[4], bfr[4];
#pragma unroll
    for (int mf = 0; mf < 4; mf++)
      af[mf] = *reinterpret_cast<const bf16x8*>(bA + offA[mf]);
#pragma unroll
    for (int nf = 0; nf < 4; nf++)
      bfr[nf] = *reinterpret_cast<const bf16x8*>(bB + offB[nf]);
    asm volatile("s_waitcnt lgkmcnt(0)" ::: "memory");  // frags in regs
    __builtin_amdgcn_sched_barrier(0);
    __builtin_amdgcn_s_barrier();                       // all waves done with cur
    if (s + 2 < NS) STAGE(cur, (s + 2) * 32);           // overwrite cur
#pragma unroll
    for (int mf = 0; mf < 4; mf++)
#pragma unroll
      for (int nf = 0; nf < 4; nf++)
        acc[mf][nf] = __builtin_amdgcn_mfma_f32_16x16x32_bf16(af[mf], bfr[nf], acc[mf][nf], 0, 0, 0);
    if (s + 1 < NS) {
      if (s + 2 < NS)
        asm volatile("s_waitcnt vmcnt(4)" ::: "memory");  // next buf landed
      else
        asm volatile("s_waitcnt vmcnt(0)" ::: "memory");  // last buf: drain
      __builtin_amdgcn_sched_barrier(0);
      __builtin_amdgcn_s_barrier();
    }
  }
#undef STAGE

  // epilogue: D row = lhi*4+reg, col = l15 (verified C/D layout)
#pragma unroll
  for (int mf = 0; mf < 4; mf++) {
#pragma unroll
    for (int nf = 0; nf < 4; nf++) {
#pragma unroll
      for (int rg = 0; rg < 4; rg++) {
        float v = acc[mf][nf][rg];
        int grow = mt * 128 + wm * 64 + mf * 16 + lhi * 4 + rg;
        int gcol = nt * 128 + wn * 64 + nf * 16 + l15;
        size_t off = ((size_t)e * CAP + grow) * NN + gcol;
        if constexpr (SILU) {
          v = v / (1.0f + __expf(-v));  // silu
          ((u16*)Cout)[off] = f2bf(v);
        } else {
          ((float*)Cout)[off] = v;
        }
      }
    }
  }
}

// ------------------------------------------- weighted combine (no atomics)
__global__ void k_combine(const float* __restrict__ yws, const int* __restrict__ slot_pos,
                          const float* __restrict__ w, float* __restrict__ out) {
  int tk = blockIdx.x;
  int t = threadIdx.x;  // 256 threads, float2 each
  int p0 = slot_pos[2 * tk], p1 = slot_pos[2 * tk + 1];
  float w0 = w[2 * tk], w1 = w[2 * tk + 1];
  float2 a = reinterpret_cast<const float2*>(yws + (size_t)p0 * HID)[t];
  float2 b = reinterpret_cast<const float2*>(yws + (size_t)p1 * HID)[t];
  float2 o;
  o.x = w0 * a.x + w1 * b.x;
  o.y = w0 * a.y + w1 * b.y;
  reinterpret_cast<float2*>(out + (size_t)tk * HID)[t] = o;
}

// ---------------------------------------------------------------- launcher
extern "C" void kernel_launch(void* const* d_in, const int* in_sizes, int n_in,
                              void* d_out, int out_size, void* d_ws, size_t ws_size,
                              hipStream_t stream) {
  const float* hs = (const float*)d_in[0];
  const float* wts = (const float*)d_in[1];
  const int* ids = (const int*)d_in[2];
  const float* W1 = (const float*)d_in[3];
  const float* W2 = (const float*)d_in[4];
  float* out = (float*)d_out;

  char* ws = (char*)d_ws;
  size_t o = 0;
  int* cnt = (int*)(ws + o);       o += 1024;
  int* slot_pos = (int*)(ws + o);  o += (size_t)NASSIGN * 4;
  int* tok_of = (int*)(ws + o);    o += (size_t)NASSIGN * 4;
  o = (o + 255) & ~(size_t)255;
  u16* Xg = (u16*)(ws + o);        o += (size_t)NASSIGN * HID * 2;      // 32 MB
  u16* hid = (u16*)(ws + o);       o += (size_t)NASSIGN * FFN * 2;      // 64 MB
  u16* W1T = (u16*)(ws + o);       o += (size_t)NEXP * HID * FFN * 2;   // 64 MB
  u16* W2T = (u16*)(ws + o);       o += (size_t)NEXP * HID * FFN * 2;   // 64 MB
  float* yws = (float*)W1T;  // overlay: W1T dead after gemm1; yws is 64 MB fp32

  hipMemsetAsync(cnt, 0, NEXP * sizeof(int), stream);
  k_route<<<(NASSIGN + 255) / 256, 256, 0, stream>>>(ids, cnt, tok_of, slot_pos);
  k_gather<<<NASSIGN / 4, 256, 0, stream>>>(hs, tok_of, Xg);
  k_transpose_bf16<HID, FFN><<<dim3(FFN / 64, HID / 64, NEXP), 256, 0, stream>>>(W1, W1T);
  k_transpose_bf16<FFN, HID><<<dim3(HID / 64, FFN / 64, NEXP), 256, 0, stream>>>(W2, W2T);
  k_gemm<HID, FFN, true><<<NEXP * (CAP / 128) * (FFN / 128), 256, 0, stream>>>(Xg, W1T, hid);
  k_gemm<FFN, HID, false><<<NEXP * (CAP / 128) * (HID / 128), 256, 0, stream>>>(hid, W2T, yws);
  k_combine<<<B_TOK, 256, 0, stream>>>(yws, slot_pos, wts, out);
}

// Round 5
// 271.739 us; speedup vs baseline: 1.2506x; 1.1151x over previous
//
#include <hip/hip_runtime.h>
#include <hip/hip_bf16.h>

#define B_TOK 16384
#define TOPK 2
#define NEXP 64
#define HID 512
#define FFN 1024
#define NASSIGN (B_TOK * TOPK)   // 32768
#define CAP (NASSIGN / NEXP)     // 512 assignments per expert (balanced)

typedef unsigned short u16;
typedef __bf16 bf16_t;
typedef bf16_t bf16x8 __attribute__((ext_vector_type(8)));
typedef float f32x4 __attribute__((ext_vector_type(4)));

__device__ __forceinline__ u16 f2bf(float f) {
  union { float f; unsigned u; } v; v.f = f;
  unsigned r = v.u + 0x7fffu + ((v.u >> 16) & 1u);  // round-to-nearest-even
  return (u16)(r >> 16);
}

#define GLOAD_LDS16(g, l)                                                     \
  __builtin_amdgcn_global_load_lds((const __attribute__((address_space(1))) void*)(g), \
                                   (__attribute__((address_space(3))) void*)(l), 16, 0, 0)

// ---------------------------------------------------------------- routing
__global__ void k_route(const int* __restrict__ ids, int* __restrict__ cnt,
                        int* __restrict__ tok_of, int* __restrict__ slot_pos) {
  int n = blockIdx.x * blockDim.x + threadIdx.x;
  if (n >= NASSIGN) return;
  int e = ids[n];
  int r = atomicAdd(&cnt[e], 1);
  int p = e * CAP + r;
  tok_of[p] = n >> 1;       // token index for sorted slot p
  slot_pos[n] = p;          // inverse map: assignment n -> sorted slot
}

// ------------------------------------------------- gather + fp32->bf16 cast
// one wave per sorted slot row; float4 loads, uint2 (4xbf16) stores
__global__ void k_gather(const float* __restrict__ hs, const int* __restrict__ tok_of,
                         u16* __restrict__ Xg) {
  int p = blockIdx.x * 4 + (threadIdx.x >> 6);
  int lane = threadIdx.x & 63;
  const float4* src = reinterpret_cast<const float4*>(hs + (size_t)tok_of[p] * HID);
  uint2* dst = reinterpret_cast<uint2*>(Xg + (size_t)p * HID);
#pragma unroll
  for (int i = 0; i < 2; i++) {
    float4 v = src[i * 64 + lane];
    uint2 o;
    o.x = (unsigned)f2bf(v.x) | ((unsigned)f2bf(v.y) << 16);
    o.y = (unsigned)f2bf(v.z) | ((unsigned)f2bf(v.w) << 16);
    dst[i * 64 + lane] = o;
  }
}

// --------------------------------- per-expert transpose + fp32->bf16 cast
// in: [E][R][C] fp32 ; out: [E][C][R] bf16.  64x64 tiles.
template <int R, int C>
__global__ void k_transpose_bf16(const float* __restrict__ in, u16* __restrict__ out) {
  __shared__ float tile[64][65];
  int e = blockIdx.z;
  int c0 = blockIdx.x * 64;
  int r0 = blockIdx.y * 64;
  const float* src = in + (size_t)e * R * C;
  u16* dst = out + (size_t)e * R * C;
  int tx = threadIdx.x & 63, ty = threadIdx.x >> 6;  // ty 0..3
#pragma unroll
  for (int p = 0; p < 16; p++) {
    int r = p * 4 + ty;
    tile[r][tx] = src[(size_t)(r0 + r) * C + (c0 + tx)];
  }
  __syncthreads();
  int rO = threadIdx.x >> 2, seg = threadIdx.x & 3;
  unsigned pk[8];
#pragma unroll
  for (int j = 0; j < 8; j++) {
    float a = tile[seg * 16 + 2 * j][rO];
    float b = tile[seg * 16 + 2 * j + 1][rO];
    pk[j] = (unsigned)f2bf(a) | ((unsigned)f2bf(b) << 16);
  }
  uint4* dp = reinterpret_cast<uint4*>(dst + (size_t)(c0 + rO) * R + r0 + seg * 16);
  dp[0] = make_uint4(pk[0], pk[1], pk[2], pk[3]);
  dp[1] = make_uint4(pk[4], pk[5], pk[6], pk[7]);
}

// ------------------------------------------------------------ grouped GEMM
// 256x256 tile, BK=64, 8 waves (2Mx4N), per-wave 128x64 out (8x4 frags).
// 4 phases per K-tile: ph0 reads A-mh0+B-nh0 (12 ds_read_b128), ph1 reads
// A-mh1+B-nh1 (12); ph2/ph3 pure MFMA from regs. Stage schedule: B(t+1)
// halves at (t,0),(t,1); A(t+2) halves at (t,2),(t,3) -- A lands in the
// CURRENT dbuf slot, legal because all ds_reads finished by ph1's barrier2.
// One vmcnt(4) per K-tile (phase 3). XOR swizzle c^(row&7) on 16B chunks via
// pre-swizzled global source + linear global_load_lds dest (rule #21).
template <int K, int NN, bool SILU>
__global__ __launch_bounds__(512, 2) void k_gemm(const u16* __restrict__ A,
                                                 const u16* __restrict__ Bw,
                                                 void* __restrict__ Cout) {
  constexpr int MT = CAP / 256;        // 2
  constexpr int NT = NN / 256;
  constexpr int NWG = NEXP * MT * NT;  // %8 == 0
  constexpr int Q = NWG / 8;
  constexpr int KT = K / 64;           // K-tiles
  int wg = (blockIdx.x % 8) * Q + blockIdx.x / 8;  // XCD chunked swizzle
  int e = wg / (MT * NT);
  int rm = wg % (MT * NT);
  int mt = rm / NT, nt = rm % NT;

  const u16* Ab = A + ((size_t)e * CAP + (size_t)mt * 256) * K;
  const u16* Bb = Bw + (size_t)e * NN * K + (size_t)nt * 256 * K;

  // LDS: A dbuf [2][256][64]bf16 = 64KB at 0; B same at 65536. 128KB total.
  __shared__ __align__(16) char smc[131072];

  int t_ = threadIdx.x;
  int lane = t_ & 63, wv = t_ >> 6;
  int wm = wv >> 2, wn = wv & 3;        // 2x4 wave grid; wave out = 128x64
  int l15 = lane & 15, lhi = lane >> 4;

  // staging: thread -> row t_>>3 (0..63 per load), chunk pos t_&7,
  // global chunk = pos ^ (row&7)
  int srow = t_ >> 3;
  int gchunk = (t_ & 7) ^ (srow & 7);
  const u16* gA = Ab + (size_t)srow * K + gchunk * 8;
  const u16* gB = Bb + (size_t)srow * K + gchunk * 8;

#define STAGE_HALF_A(tn, j)                                                  \
  do {                                                                       \
    char* d_ = smc + ((tn) & 1) * 32768 + (j) * 16384 + wv * 1024;           \
    const u16* s_ = gA + (size_t)((j) * 128) * K + (tn) * 64;                \
    GLOAD_LDS16(s_, d_);                                                     \
    GLOAD_LDS16(s_ + (size_t)64 * K, d_ + 8192);                             \
  } while (0)
#define STAGE_HALF_B(tn, j)                                                  \
  do {                                                                       \
    char* d_ = smc + 65536 + ((tn) & 1) * 32768 + (j) * 16384 + wv * 1024;   \
    const u16* s_ = gB + (size_t)((j) * 128) * K + (tn) * 64;                \
    GLOAD_LDS16(s_, d_);                                                     \
    GLOAD_LDS16(s_ + (size_t)64 * K, d_ + 8192);                             \
  } while (0)

  f32x4 acc[8][4];
#pragma unroll
  for (int i = 0; i < 8; i++)
#pragma unroll
    for (int j = 0; j < 4; j++) {
      f32x4 z = {0.f, 0.f, 0.f, 0.f};
      acc[i][j] = z;
    }
  bf16x8 a[8][2], b[4][2];

  // ds_read offsets: row*128 + (chunk ^ (l15&7))*16 ; chunk = kk*4+lhi
  int c0 = (lhi ^ (l15 & 7)) * 16;
  int c1 = ((4 + lhi) ^ (l15 & 7)) * 16;
  int aoff0 = (wm * 128 + l15) * 128 + c0;
  int aoff1 = (wm * 128 + l15) * 128 + c1;
  int boff0 = (wn * 64 + l15) * 128 + c0;
  int boff1 = (wn * 64 + l15) * 128 + c1;

  // prologue: A(0) both halves, B(0) both halves, A(1) both halves
  STAGE_HALF_A(0, 0); STAGE_HALF_A(0, 1);
  STAGE_HALF_B(0, 0); STAGE_HALF_B(0, 1);
  if (KT > 1) {
    STAGE_HALF_A(1, 0); STAGE_HALF_A(1, 1);
    asm volatile("s_waitcnt vmcnt(4)" ::: "memory");  // tile 0 landed
  } else {
    asm volatile("s_waitcnt vmcnt(0)" ::: "memory");
  }
  __builtin_amdgcn_sched_barrier(0);
  __builtin_amdgcn_s_barrier();

#define MFMA_QUAD(mh, nh)                                                    \
  do {                                                                       \
    __builtin_amdgcn_s_setprio(1);                                           \
    _Pragma("unroll") for (int mf = 0; mf < 4; mf++)                         \
        _Pragma("unroll") for (int nf = 0; nf < 2; nf++)                     \
            _Pragma("unroll") for (int kk = 0; kk < 2; kk++)                 \
                acc[(mh)*4 + mf][(nh)*2 + nf] = __builtin_amdgcn_mfma_f32_16x16x32_bf16( \
                    a[(mh)*4 + mf][kk], b[(nh)*2 + nf][kk], acc[(mh)*4 + mf][(nh)*2 + nf], 0, 0, 0); \
    __builtin_amdgcn_s_setprio(0);                                           \
  } while (0)

  for (int t = 0; t < KT; t++) {
    const char* pAc = smc + (t & 1) * 32768;
    const char* pBc = smc + 65536 + (t & 1) * 32768;

    // ---- phase 0: read A-mh0 + B-nh0; stage B(t+1) h0
#pragma unroll
    for (int mf = 0; mf < 4; mf++) {
      a[mf][0] = *reinterpret_cast<const bf16x8*>(pAc + aoff0 + mf * 2048);
      a[mf][1] = *reinterpret_cast<const bf16x8*>(pAc + aoff1 + mf * 2048);
    }
#pragma unroll
    for (int nf = 0; nf < 2; nf++) {
      b[nf][0] = *reinterpret_cast<const bf16x8*>(pBc + boff0 + nf * 2048);
      b[nf][1] = *reinterpret_cast<const bf16x8*>(pBc + boff1 + nf * 2048);
    }
    if (t + 1 < KT) STAGE_HALF_B(t + 1, 0);
    __builtin_amdgcn_s_barrier();
    asm volatile("s_waitcnt lgkmcnt(0)" ::: "memory");
    __builtin_amdgcn_sched_barrier(0);
    MFMA_QUAD(0, 0);
    __builtin_amdgcn_s_barrier();

    // ---- phase 1: read A-mh1 + B-nh1; stage B(t+1) h1
#pragma unroll
    for (int mf = 0; mf < 4; mf++) {
      a[4 + mf][0] = *reinterpret_cast<const bf16x8*>(pAc + aoff0 + (4 + mf) * 2048);
      a[4 + mf][1] = *reinterpret_cast<const bf16x8*>(pAc + aoff1 + (4 + mf) * 2048);
    }
#pragma unroll
    for (int nf = 0; nf < 2; nf++) {
      b[2 + nf][0] = *reinterpret_cast<const bf16x8*>(pBc + boff0 + (2 + nf) * 2048);
      b[2 + nf][1] = *reinterpret_cast<const bf16x8*>(pBc + boff1 + (2 + nf) * 2048);
    }
    if (t + 1 < KT) STAGE_HALF_B(t + 1, 1);
    __builtin_amdgcn_s_barrier();
    asm volatile("s_waitcnt lgkmcnt(0)" ::: "memory");
    __builtin_amdgcn_sched_barrier(0);
    MFMA_QUAD(0, 1);
    __builtin_amdgcn_s_barrier();

    // ---- phase 2: pure MFMA; stage A(t+2) h0 (into cur slot -- reads done)
    if (t + 2 < KT) STAGE_HALF_A(t + 2, 0);
    __builtin_amdgcn_s_barrier();
    MFMA_QUAD(1, 0);
    __builtin_amdgcn_s_barrier();

    // ---- phase 3: pure MFMA; stage A(t+2) h1; counted vmcnt
    if (t + 2 < KT) STAGE_HALF_A(t + 2, 1);
    __builtin_amdgcn_s_barrier();
    MFMA_QUAD(1, 1);
    if (t + 2 < KT)
      asm volatile("s_waitcnt vmcnt(4)" ::: "memory");  // tile t+1 resident
    else
      asm volatile("s_waitcnt vmcnt(0)" ::: "memory");  // drain tail
    __builtin_amdgcn_sched_barrier(0);
    __builtin_amdgcn_s_barrier();
  }
#undef STAGE_HALF_A
#undef STAGE_HALF_B
#undef MFMA_QUAD

  // epilogue: D row = lhi*4+reg, col = l15 (verified C/D layout)
#pragma unroll
  for (int mf = 0; mf < 8; mf++) {
#pragma unroll
    for (int nf = 0; nf < 4; nf++) {
#pragma unroll
      for (int rg = 0; rg < 4; rg++) {
        float v = acc[mf][nf][rg];
        int grow = mt * 256 + wm * 128 + mf * 16 + lhi * 4 + rg;
        int gcol = nt * 256 + wn * 64 + nf * 16 + l15;
        size_t off = ((size_t)e * CAP + grow) * NN + gcol;
        if constexpr (SILU) {
          v = v / (1.0f + __expf(-v));  // silu
          ((u16*)Cout)[off] = f2bf(v);
        } else {
          ((float*)Cout)[off] = v;
        }
      }
    }
  }
}

// ------------------------------------------- weighted combine (no atomics)
__global__ void k_combine(const float* __restrict__ yws, const int* __restrict__ slot_pos,
                          const float* __restrict__ w, float* __restrict__ out) {
  int tk = blockIdx.x;
  int t = threadIdx.x;  // 256 threads, float2 each
  int p0 = slot_pos[2 * tk], p1 = slot_pos[2 * tk + 1];
  float w0 = w[2 * tk], w1 = w[2 * tk + 1];
  float2 a = reinterpret_cast<const float2*>(yws + (size_t)p0 * HID)[t];
  float2 b = reinterpret_cast<const float2*>(yws + (size_t)p1 * HID)[t];
  float2 o;
  o.x = w0 * a.x + w1 * b.x;
  o.y = w0 * a.y + w1 * b.y;
  reinterpret_cast<float2*>(out + (size_t)tk * HID)[t] = o;
}

// ---------------------------------------------------------------- launcher
extern "C" void kernel_launch(void* const* d_in, const int* in_sizes, int n_in,
                              void* d_out, int out_size, void* d_ws, size_t ws_size,
                              hipStream_t stream) {
  const float* hs = (const float*)d_in[0];
  const float* wts = (const float*)d_in[1];
  const int* ids = (const int*)d_in[2];
  const float* W1 = (const float*)d_in[3];
  const float* W2 = (const float*)d_in[4];
  float* out = (float*)d_out;

  char* ws = (char*)d_ws;
  size_t o = 0;
  int* cnt = (int*)(ws + o);       o += 1024;
  int* slot_pos = (int*)(ws + o);  o += (size_t)NASSIGN * 4;
  int* tok_of = (int*)(ws + o);    o += (size_t)NASSIGN * 4;
  o = (o + 255) & ~(size_t)255;
  u16* Xg = (u16*)(ws + o);        o += (size_t)NASSIGN * HID * 2;      // 32 MB
  u16* hid = (u16*)(ws + o);       o += (size_t)NASSIGN * FFN * 2;      // 64 MB
  u16* W1T = (u16*)(ws + o);       o += (size_t)NEXP * HID * FFN * 2;   // 64 MB
  u16* W2T = (u16*)(ws + o);       o += (size_t)NEXP * HID * FFN * 2;   // 64 MB
  float* yws = (float*)W1T;  // overlay: W1T dead after gemm1; yws is 64 MB fp32

  hipMemsetAsync(cnt, 0, NEXP * sizeof(int), stream);
  k_route<<<(NASSIGN + 255) / 256, 256, 0, stream>>>(ids, cnt, tok_of, slot_pos);
  k_gather<<<NASSIGN / 4, 256, 0, stream>>>(hs, tok_of, Xg);
  k_transpose_bf16<HID, FFN><<<dim3(FFN / 64, HID / 64, NEXP), 256, 0, stream>>>(W1, W1T);
  k_transpose_bf16<FFN, HID><<<dim3(HID / 64, FFN / 64, NEXP), 256, 0, stream>>>(W2, W2T);
  k_gemm<HID, FFN, true><<<NEXP * (CAP / 256) * (FFN / 256), 512, 0, stream>>>(Xg, W1T, hid);
  k_gemm<FFN, HID, false><<<NEXP * (CAP / 256) * (HID / 256), 512, 0, stream>>>(hid, W2T, yws);
  k_combine<<<B_TOK, 256, 0, stream>>>(yws, slot_pos, wts, out);
}

// Round 6
// 226.391 us; speedup vs baseline: 1.5011x; 1.2003x over previous
//
#include <hip/hip_runtime.h>
#include <hip/hip_bf16.h>

#define B_TOK 16384
#define TOPK 2
#define NEXP 64
#define HID 512
#define FFN 1024
#define NASSIGN (B_TOK * TOPK)   // 32768
#define CAP (NASSIGN / NEXP)     // 512 assignments per expert (balanced)

typedef unsigned short u16;
typedef __bf16 bf16_t;
typedef bf16_t bf16x8 __attribute__((ext_vector_type(8)));
typedef float f32x4 __attribute__((ext_vector_type(4)));

__device__ __forceinline__ u16 f2bf(float f) {
  union { float f; unsigned u; } v; v.f = f;
  unsigned r = v.u + 0x7fffu + ((v.u >> 16) & 1u);  // round-to-nearest-even
  return (u16)(r >> 16);
}
__device__ __forceinline__ unsigned pkbf(float a, float b) {
  return (unsigned)f2bf(a) | ((unsigned)f2bf(b) << 16);
}
__device__ __forceinline__ float bf2f(unsigned u16v) {
  union { unsigned u; float f; } v; v.u = u16v << 16; return v.f;
}

#define GLOAD_LDS16(g, l)                                                     \
  __builtin_amdgcn_global_load_lds((const __attribute__((address_space(1))) void*)(g), \
                                   (__attribute__((address_space(3))) void*)(l), 16, 0, 0)

// ---------------------------------------------------------------- routing
__global__ void k_route(const int* __restrict__ ids, int* __restrict__ cnt,
                        int* __restrict__ tok_of, int* __restrict__ slot_pos) {
  int n = blockIdx.x * blockDim.x + threadIdx.x;
  if (n >= NASSIGN) return;
  int e = ids[n];
  int r = atomicAdd(&cnt[e], 1);
  int p = e * CAP + r;
  tok_of[p] = n >> 1;       // token index for sorted slot p
  slot_pos[n] = p;          // inverse map: assignment n -> sorted slot
}

// ------------------------------------------------- gather + fp32->bf16 cast
__global__ void k_gather(const float* __restrict__ hs, const int* __restrict__ tok_of,
                         u16* __restrict__ Xg) {
  int p = blockIdx.x * 4 + (threadIdx.x >> 6);
  int lane = threadIdx.x & 63;
  const float4* src = reinterpret_cast<const float4*>(hs + (size_t)tok_of[p] * HID);
  uint2* dst = reinterpret_cast<uint2*>(Xg + (size_t)p * HID);
#pragma unroll
  for (int i = 0; i < 2; i++) {
    float4 v = src[i * 64 + lane];
    uint2 o;
    o.x = pkbf(v.x, v.y);
    o.y = pkbf(v.z, v.w);
    dst[i * 64 + lane] = o;
  }
}

// ------------------------------------------------------------ grouped GEMM
// C[e*CAP+m][n] = sum_k A[e*CAP+m][k] * W[e][k][n], W read as raw fp32 and
// transposed+converted to bf16 [n][k] LDS tiles inside the kernel (no prepass).
// 256x256 tile, BK=64, 8 waves (2Mx4N). Per K-tile, 4 phases:
//  ph0: ds_read a03(8)+b01(4); issue W-loads L0..3;        bar; Q(0,0); bar
//  ph1: ds_read b23(4); issue L4..7; cvt+write lo-half B;  bar; Q(0,1); bar
//  ph2: ds_read a47(8); cvt+write hi-half B;               bar; Q(1,0); bar
//  ph3: A(t+2) global_load_lds (after all-waves lgkm+bar); bar; Q(1,1); bar
// Every phase ends its read/write block with lgkmcnt(0)+sched_barrier BEFORE
// s_barrier, so cross-wave LDS reuse is race-free. vmcnt handled implicitly:
// compiler-counted waits on L consumption force A-DMA retirement in order.
// Swizzles (both-sides, rule #21): A chunk c -> c^(row&7) (gload_lds path,
// pre-swizzled global source); B chunk c -> c^S(n), S(n)=(n^(n>>3))&7
// (reg-staged writes), matching ds_read addresses.
template <int K, int NN, bool SILU>
__global__ __launch_bounds__(512, 2) void k_gemm(const u16* __restrict__ A,
                                                 const float* __restrict__ Wf,
                                                 u16* __restrict__ Cout) {
  constexpr int MT = CAP / 256;        // 2
  constexpr int NT = NN / 256;
  constexpr int NWG = NEXP * MT * NT;  // %8 == 0
  constexpr int Q = NWG / 8;
  constexpr int KT = K / 64;           // K-tiles (8 or 16)
  int wg = (blockIdx.x % 8) * Q + blockIdx.x / 8;  // XCD chunked swizzle
  int e = wg / (MT * NT);
  int rm = wg % (MT * NT);
  int mt = rm / NT, nt = rm % NT;

  const u16* Ab = A + ((size_t)e * CAP + (size_t)mt * 256) * K;

  // LDS: A dbuf 2x32KB at 0; B dbuf 2x32KB at 65536. 128KB.
  __shared__ __align__(16) char smc[131072];

  int t_ = threadIdx.x;
  int lane = t_ & 63, wv = t_ >> 6;
  int wm = wv >> 2, wn = wv & 3;        // 2x4 wave grid; wave out = 128x64
  int l15 = lane & 15, lhi = lane >> 4;

  // ---- A staging (global_load_lds): row t_>>3, chunk pos t_&7, src chunk ^row&7
  int srow = t_ >> 3;
  int gchunk = (t_ & 7) ^ (srow & 7);
  const u16* gA = Ab + (size_t)srow * K + gchunk * 8;
#define STAGE_HALF_A(tn, j)                                                  \
  do {                                                                       \
    char* d_ = smc + ((tn) & 1) * 32768 + (j) * 16384 + wv * 1024;           \
    const u16* s_ = gA + (size_t)((j) * 128) * K + (tn) * 64;                \
    GLOAD_LDS16(s_, d_);                                                     \
    GLOAD_LDS16(s_ + (size_t)64 * K, d_ + 8192);                             \
  } while (0)

  // ---- B staging (reg-staged transpose+cvt from fp32 W[k][n])
  // thread unit: k0=kunit*8 (8 rows), n0=nunit*4 (4 cols)
  int kunit = t_ >> 6;                  // 0..7
  int nunit = t_ & 63;                  // 0..63
  const float* gWb = Wf + (size_t)e * K * NN + (size_t)(kunit * 8) * NN +
                     (size_t)nt * 256 + nunit * 4;
  int wbo[4];                           // byte offsets of the 4 write slots
#pragma unroll
  for (int i = 0; i < 4; i++) {
    int n = nunit * 4 + i;
    int S = (n ^ (n >> 3)) & 7;
    wbo[i] = n * 128 + ((kunit ^ S) << 4);
  }

  f32x4 acc[8][4];
#pragma unroll
  for (int i = 0; i < 8; i++)
#pragma unroll
    for (int j = 0; j < 4; j++) {
      f32x4 z = {0.f, 0.f, 0.f, 0.f};
      acc[i][j] = z;
    }
  bf16x8 a[4][2], b[4][2];

  // ---- fragment read offsets
  int aof0 = (wm * 128 + l15) * 128 + ((lhi ^ (l15 & 7)) << 4);
  int aof1 = (wm * 128 + l15) * 128 + (((4 + lhi) ^ (l15 & 7)) << 4);
  int boff[4][2];
#pragma unroll
  for (int nf = 0; nf < 4; nf++) {
    int r = wn * 64 + nf * 16 + l15;
    int Sr = (r ^ (r >> 3)) & 7;
    boff[nf][0] = r * 128 + ((lhi ^ Sr) << 4);
    boff[nf][1] = r * 128 + (((4 + lhi) ^ Sr) << 4);
  }

#define LGKM0_BAR()                                                          \
  do {                                                                       \
    asm volatile("s_waitcnt lgkmcnt(0)" ::: "memory");                       \
    __builtin_amdgcn_sched_barrier(0);                                       \
    __builtin_amdgcn_s_barrier();                                            \
  } while (0)

#define MFMA_QUAD(mh, nh)                                                    \
  do {                                                                       \
    __builtin_amdgcn_s_setprio(1);                                           \
    _Pragma("unroll") for (int mf = 0; mf < 4; mf++)                         \
        _Pragma("unroll") for (int nf = 0; nf < 2; nf++)                     \
            _Pragma("unroll") for (int kk = 0; kk < 2; kk++)                 \
                acc[(mh)*4 + mf][(nh)*2 + nf] = __builtin_amdgcn_mfma_f32_16x16x32_bf16( \
                    a[mf][kk], b[(nh)*2 + nf][kk], acc[(mh)*4 + mf][(nh)*2 + nf], 0, 0, 0); \
    __builtin_amdgcn_s_setprio(0);                                           \
  } while (0)

  // ---- prologue: A(0), A(1) via DMA; B(0) reg-staged into slot 0
  STAGE_HALF_A(0, 0); STAGE_HALF_A(0, 1);
  if (KT > 1) { STAGE_HALF_A(1, 0); STAGE_HALF_A(1, 1); }
  {
    float4 P[8];
#pragma unroll
    for (int j = 0; j < 8; j++)
      P[j] = *reinterpret_cast<const float4*>(gWb + (size_t)j * NN);
    char* wB = smc + 65536;  // slot 0
#pragma unroll
    for (int i = 0; i < 4; i++) {
      uint4 v;
      v.x = pkbf(P[0][i], P[1][i]); v.y = pkbf(P[2][i], P[3][i]);
      v.z = pkbf(P[4][i], P[5][i]); v.w = pkbf(P[6][i], P[7][i]);
      *reinterpret_cast<uint4*>(wB + wbo[i]) = v;
    }
  }
  LGKM0_BAR();

  for (int t = 0; t < KT; t++) {
    const char* pA = smc + (t & 1) * 32768;
    const char* pB = smc + 65536 + (t & 1) * 32768;
    char* wB = smc + 65536 + ((t + 1) & 1) * 32768;
    float4 L0, L1, L2, L3, L4, L5, L6, L7;

    // ---------------- phase 0
#pragma unroll
    for (int mf = 0; mf < 4; mf++) {
      a[mf][0] = *reinterpret_cast<const bf16x8*>(pA + aof0 + mf * 2048);
      a[mf][1] = *reinterpret_cast<const bf16x8*>(pA + aof1 + mf * 2048);
    }
#pragma unroll
    for (int nf = 0; nf < 2; nf++) {
      b[nf][0] = *reinterpret_cast<const bf16x8*>(pB + boff[nf][0]);
      b[nf][1] = *reinterpret_cast<const bf16x8*>(pB + boff[nf][1]);
    }
    if (t + 1 < KT) {
      const float* g = gWb + (size_t)(t + 1) * 64 * NN;
      L0 = *reinterpret_cast<const float4*>(g);
      L1 = *reinterpret_cast<const float4*>(g + (size_t)1 * NN);
      L2 = *reinterpret_cast<const float4*>(g + (size_t)2 * NN);
      L3 = *reinterpret_cast<const float4*>(g + (size_t)3 * NN);
    }
    LGKM0_BAR();
    MFMA_QUAD(0, 0);
    __builtin_amdgcn_s_barrier();

    // ---------------- phase 1
#pragma unroll
    for (int nf = 0; nf < 2; nf++) {
      b[2 + nf][0] = *reinterpret_cast<const bf16x8*>(pB + boff[2 + nf][0]);
      b[2 + nf][1] = *reinterpret_cast<const bf16x8*>(pB + boff[2 + nf][1]);
    }
    if (t + 1 < KT) {
      const float* g = gWb + (size_t)(t + 1) * 64 * NN;
      L4 = *reinterpret_cast<const float4*>(g + (size_t)4 * NN);
      L5 = *reinterpret_cast<const float4*>(g + (size_t)5 * NN);
      L6 = *reinterpret_cast<const float4*>(g + (size_t)6 * NN);
      L7 = *reinterpret_cast<const float4*>(g + (size_t)7 * NN);
      // lo half (k0..k3) -> bytes 0..7 of each 16B slot
#pragma unroll
      for (int i = 0; i < 4; i++) {
        uint2 v;
        v.x = pkbf(L0[i], L1[i]); v.y = pkbf(L2[i], L3[i]);
        *reinterpret_cast<uint2*>(wB + wbo[i]) = v;
      }
    }
    LGKM0_BAR();
    MFMA_QUAD(0, 1);
    __builtin_amdgcn_s_barrier();

    // ---------------- phase 2
#pragma unroll
    for (int mf = 0; mf < 4; mf++) {
      a[mf][0] = *reinterpret_cast<const bf16x8*>(pA + aof0 + (4 + mf) * 2048);
      a[mf][1] = *reinterpret_cast<const bf16x8*>(pA + aof1 + (4 + mf) * 2048);
    }
    if (t + 1 < KT) {
      // hi half (k4..k7) -> bytes 8..15
#pragma unroll
      for (int i = 0; i < 4; i++) {
        uint2 v;
        v.x = pkbf(L4[i], L5[i]); v.y = pkbf(L6[i], L7[i]);
        *reinterpret_cast<uint2*>(wB + wbo[i] + 8) = v;
      }
    }
    LGKM0_BAR();
    MFMA_QUAD(1, 0);
    __builtin_amdgcn_s_barrier();

    // ---------------- phase 3 (A-DMA safe: all waves' A-reads done at ph2 bar)
    if (t + 2 < KT) { STAGE_HALF_A(t + 2, 0); STAGE_HALF_A(t + 2, 1); }
    __builtin_amdgcn_s_barrier();
    MFMA_QUAD(1, 1);
    __builtin_amdgcn_s_barrier();
  }
#undef STAGE_HALF_A
#undef MFMA_QUAD
#undef LGKM0_BAR

  // epilogue: D row = lhi*4+reg, col = l15 (verified C/D layout); bf16 out
#pragma unroll
  for (int mf = 0; mf < 8; mf++) {
#pragma unroll
    for (int nf = 0; nf < 4; nf++) {
#pragma unroll
      for (int rg = 0; rg < 4; rg++) {
        float v = acc[mf][nf][rg];
        int grow = mt * 256 + wm * 128 + mf * 16 + lhi * 4 + rg;
        int gcol = nt * 256 + wn * 64 + nf * 16 + l15;
        size_t off = ((size_t)e * CAP + grow) * NN + gcol;
        if constexpr (SILU) v = v / (1.0f + __expf(-v));  // silu
        Cout[off] = f2bf(v);
      }
    }
  }
}

// ------------------------------------------- weighted combine (no atomics)
__global__ void k_combine(const u16* __restrict__ yws, const int* __restrict__ slot_pos,
                          const float* __restrict__ w, float* __restrict__ out) {
  int tk = blockIdx.x;
  int t = threadIdx.x;  // 256 threads, 2 elems each
  int p0 = slot_pos[2 * tk], p1 = slot_pos[2 * tk + 1];
  float w0 = w[2 * tk], w1 = w[2 * tk + 1];
  unsigned ua = reinterpret_cast<const unsigned*>(yws + (size_t)p0 * HID)[t];
  unsigned ub = reinterpret_cast<const unsigned*>(yws + (size_t)p1 * HID)[t];
  float2 o;
  o.x = w0 * bf2f(ua & 0xffffu) + w1 * bf2f(ub & 0xffffu);
  o.y = w0 * bf2f(ua >> 16) + w1 * bf2f(ub >> 16);
  reinterpret_cast<float2*>(out + (size_t)tk * HID)[t] = o;
}

// ---------------------------------------------------------------- launcher
extern "C" void kernel_launch(void* const* d_in, const int* in_sizes, int n_in,
                              void* d_out, int out_size, void* d_ws, size_t ws_size,
                              hipStream_t stream) {
  const float* hs = (const float*)d_in[0];
  const float* wts = (const float*)d_in[1];
  const int* ids = (const int*)d_in[2];
  const float* W1 = (const float*)d_in[3];
  const float* W2 = (const float*)d_in[4];
  float* out = (float*)d_out;

  char* ws = (char*)d_ws;
  size_t o = 0;
  int* cnt = (int*)(ws + o);       o += 1024;
  int* slot_pos = (int*)(ws + o);  o += (size_t)NASSIGN * 4;
  int* tok_of = (int*)(ws + o);    o += (size_t)NASSIGN * 4;
  o = (o + 255) & ~(size_t)255;
  u16* Xg = (u16*)(ws + o);        o += (size_t)NASSIGN * HID * 2;      // 32 MB
  u16* hid = (u16*)(ws + o);       o += (size_t)NASSIGN * FFN * 2;      // 64 MB
  u16* yws = (u16*)(ws + o);       o += (size_t)NASSIGN * HID * 2;      // 32 MB

  hipMemsetAsync(cnt, 0, NEXP * sizeof(int), stream);
  k_route<<<(NASSIGN + 255) / 256, 256, 0, stream>>>(ids, cnt, tok_of, slot_pos);
  k_gather<<<NASSIGN / 4, 256, 0, stream>>>(hs, tok_of, Xg);
  k_gemm<HID, FFN, true><<<NEXP * (CAP / 256) * (FFN / 256), 512, 0, stream>>>(Xg, W1, hid);
  k_gemm<FFN, HID, false><<<NEXP * (CAP / 256) * (HID / 256), 512, 0, stream>>>(hid, W2, yws);
  k_combine<<<B_TOK, 256, 0, stream>>>(yws, slot_pos, wts, out);
}

// Round 7
// 224.129 us; speedup vs baseline: 1.5162x; 1.0101x over previous
//
#include <hip/hip_runtime.h>
#include <hip/hip_bf16.h>

#define B_TOK 16384
#define TOPK 2
#define NEXP 64
#define HID 512
#define FFN 1024
#define NASSIGN (B_TOK * TOPK)   // 32768
#define CAP (NASSIGN / NEXP)     // 512 assignments per expert (balanced)

typedef unsigned short u16;
typedef __bf16 bf16_t;
typedef bf16_t bf16x8 __attribute__((ext_vector_type(8)));
typedef float f32x4 __attribute__((ext_vector_type(4)));

__device__ __forceinline__ u16 f2bf(float f) {
  union { float f; unsigned u; } v; v.f = f;
  unsigned r = v.u + 0x7fffu + ((v.u >> 16) & 1u);  // round-to-nearest-even
  return (u16)(r >> 16);
}
__device__ __forceinline__ unsigned pkbf(float a, float b) {
  return (unsigned)f2bf(a) | ((unsigned)f2bf(b) << 16);
}
__device__ __forceinline__ float bf2f(unsigned u16v) {
  union { unsigned u; float f; } v; v.u = u16v << 16; return v.f;
}

#define GLOAD_LDS16(g, l)                                                     \
  __builtin_amdgcn_global_load_lds((const __attribute__((address_space(1))) void*)(g), \
                                   (__attribute__((address_space(3))) void*)(l), 16, 0, 0)

// ---------------------------------------------------------------- routing
__global__ void k_route(const int* __restrict__ ids, int* __restrict__ cnt,
                        int* __restrict__ tok_of, int* __restrict__ slot_pos) {
  int n = blockIdx.x * blockDim.x + threadIdx.x;
  if (n >= NASSIGN) return;
  int e = ids[n];
  int r = atomicAdd(&cnt[e], 1);
  int p = e * CAP + r;
  tok_of[p] = n >> 1;       // token index for sorted slot p
  slot_pos[n] = p;          // inverse map: assignment n -> sorted slot
}

// ------------------------------------------------- gather + fp32->bf16 cast
__global__ void k_gather(const float* __restrict__ hs, const int* __restrict__ tok_of,
                         u16* __restrict__ Xg) {
  int p = blockIdx.x * 4 + (threadIdx.x >> 6);
  int lane = threadIdx.x & 63;
  const float4* src = reinterpret_cast<const float4*>(hs + (size_t)tok_of[p] * HID);
  uint2* dst = reinterpret_cast<uint2*>(Xg + (size_t)p * HID);
#pragma unroll
  for (int i = 0; i < 2; i++) {
    float4 v = src[i * 64 + lane];
    uint2 o;
    o.x = pkbf(v.x, v.y);
    o.y = pkbf(v.z, v.w);
    dst[i * 64 + lane] = o;
  }
}

// ------------------------------------------------------------ grouped GEMM
// C[e*CAP+m][n] = sum_k A[e*CAP+m][k] * W[e][k][n], W read as raw fp32 and
// transposed+converted to bf16 [n][k] LDS tiles in-kernel (no prepass).
// 256x256 tile, BK=64, 8 waves (2Mx4N). Per K-tile, 4 phases:
//  ph0: ds_read a03(8)+b01(4); issue W-loads L0..3(t+1);   lgkm0 bar; Q(0,0); bar
//  ph1: ds_read b23(4);        issue W-loads L4..7(t+1);   lgkm0 bar; Q(0,1); bar
//  ph2: ds_read a47(8);                                    lgkm0 bar; Q(1,0); bar
//  ph3: A(t+2) DMA (safe: all A-reads drained at ph2 bar); vmcnt(4) counted
//       (only ADMA(t+2) left in flight; L0..7 got 2-3 phases of flight);
//       4x uint4 swizzled B-writes (32-bank conflict-free);  lgkm0 bar; Q(1,1); bar
// vmcnt never drains to 0 mid-loop (T4). In-order VMEM retirement also
// guarantees ADMA(t+1) resident before tile t+1's A-reads.
// Swizzles (both-sides, rule #21): A chunk c -> c^(row&7) (pre-swizzled global
// source, linear gload_lds dest); B chunk c -> c^S(n), S(n)=(n^(n>>3))&7
// (reg-staged writes), matching ds_read addresses.
template <int K, int NN, bool SILU>
__global__ __launch_bounds__(512, 2) void k_gemm(const u16* __restrict__ A,
                                                 const float* __restrict__ Wf,
                                                 u16* __restrict__ Cout) {
  constexpr int MT = CAP / 256;        // 2
  constexpr int NT = NN / 256;
  constexpr int NWG = NEXP * MT * NT;  // %8 == 0
  constexpr int Q = NWG / 8;
  constexpr int KT = K / 64;           // K-tiles (8 or 16)
  int wg = (blockIdx.x % 8) * Q + blockIdx.x / 8;  // XCD chunked swizzle
  int e = wg / (MT * NT);
  int rm = wg % (MT * NT);
  int mt = rm / NT, nt = rm % NT;

  const u16* Ab = A + ((size_t)e * CAP + (size_t)mt * 256) * K;

  // LDS: A dbuf 2x32KB at 0; B dbuf 2x32KB at 65536. 128KB.
  __shared__ __align__(16) char smc[131072];

  int t_ = threadIdx.x;
  int lane = t_ & 63, wv = t_ >> 6;
  int wm = wv >> 2, wn = wv & 3;        // 2x4 wave grid; wave out = 128x64
  int l15 = lane & 15, lhi = lane >> 4;

  // ---- A staging (global_load_lds): row t_>>3, chunk pos t_&7, src chunk ^row&7
  int srow = t_ >> 3;
  int gchunk = (t_ & 7) ^ (srow & 7);
  const u16* gA = Ab + (size_t)srow * K + gchunk * 8;
#define STAGE_HALF_A(tn, j)                                                  \
  do {                                                                       \
    char* d_ = smc + ((tn) & 1) * 32768 + (j) * 16384 + wv * 1024;           \
    const u16* s_ = gA + (size_t)((j) * 128) * K + (tn) * 64;                \
    GLOAD_LDS16(s_, d_);                                                     \
    GLOAD_LDS16(s_ + (size_t)64 * K, d_ + 8192);                             \
  } while (0)

  // ---- B staging (reg-staged transpose+cvt from fp32 W[k][n])
  // thread unit: k0=kunit*8 (8 rows), n0=nunit*4 (4 cols)
  int kunit = t_ >> 6;                  // 0..7
  int nunit = t_ & 63;                  // 0..63
  const float* gWb = Wf + (size_t)e * K * NN + (size_t)(kunit * 8) * NN +
                     (size_t)nt * 256 + nunit * 4;
  int wbo[4];                           // byte offsets of the 4 write slots
#pragma unroll
  for (int i = 0; i < 4; i++) {
    int n = nunit * 4 + i;
    int S = (n ^ (n >> 3)) & 7;
    wbo[i] = n * 128 + ((kunit ^ S) << 4);
  }

  f32x4 acc[8][4];
#pragma unroll
  for (int i = 0; i < 8; i++)
#pragma unroll
    for (int j = 0; j < 4; j++) {
      f32x4 z = {0.f, 0.f, 0.f, 0.f};
      acc[i][j] = z;
    }
  bf16x8 a[4][2], b[4][2];

  // ---- fragment read offsets
  int aof0 = (wm * 128 + l15) * 128 + ((lhi ^ (l15 & 7)) << 4);
  int aof1 = (wm * 128 + l15) * 128 + (((4 + lhi) ^ (l15 & 7)) << 4);
  int boff[4][2];
#pragma unroll
  for (int nf = 0; nf < 4; nf++) {
    int r = wn * 64 + nf * 16 + l15;
    int Sr = (r ^ (r >> 3)) & 7;
    boff[nf][0] = r * 128 + ((lhi ^ Sr) << 4);
    boff[nf][1] = r * 128 + (((4 + lhi) ^ Sr) << 4);
  }

#define LGKM0_BAR()                                                          \
  do {                                                                       \
    asm volatile("s_waitcnt lgkmcnt(0)" ::: "memory");                       \
    __builtin_amdgcn_sched_barrier(0);                                       \
    __builtin_amdgcn_s_barrier();                                            \
  } while (0)

#define MFMA_QUAD(mh, nh)                                                    \
  do {                                                                       \
    __builtin_amdgcn_s_setprio(1);                                           \
    _Pragma("unroll") for (int mf = 0; mf < 4; mf++)                         \
        _Pragma("unroll") for (int nf = 0; nf < 2; nf++)                     \
            _Pragma("unroll") for (int kk = 0; kk < 2; kk++)                 \
                acc[(mh)*4 + mf][(nh)*2 + nf] = __builtin_amdgcn_mfma_f32_16x16x32_bf16( \
                    a[mf][kk], b[(nh)*2 + nf][kk], acc[(mh)*4 + mf][(nh)*2 + nf], 0, 0, 0); \
    __builtin_amdgcn_s_setprio(0);                                           \
  } while (0)

  // ---- prologue: A(0), A(1) via DMA; B(0) reg-staged into slot 0
  STAGE_HALF_A(0, 0); STAGE_HALF_A(0, 1);
  if (KT > 1) { STAGE_HALF_A(1, 0); STAGE_HALF_A(1, 1); }
  {
    float4 P[8];
#pragma unroll
    for (int j = 0; j < 8; j++)
      P[j] = *reinterpret_cast<const float4*>(gWb + (size_t)j * NN);
    char* wB = smc + 65536;  // slot 0
#pragma unroll
    for (int i = 0; i < 4; i++) {
      uint4 v;
      v.x = pkbf(P[0][i], P[1][i]); v.y = pkbf(P[2][i], P[3][i]);
      v.z = pkbf(P[4][i], P[5][i]); v.w = pkbf(P[6][i], P[7][i]);
      *reinterpret_cast<uint4*>(wB + wbo[i]) = v;
    }
  }
  asm volatile("s_waitcnt vmcnt(0)" ::: "memory");  // A(0),A(1) resident (once)
  LGKM0_BAR();

  for (int t = 0; t < KT; t++) {
    const char* pA = smc + (t & 1) * 32768;
    const char* pB = smc + 65536 + (t & 1) * 32768;
    char* wB = smc + 65536 + ((t + 1) & 1) * 32768;
    float4 L0, L1, L2, L3, L4, L5, L6, L7;

    // ---------------- phase 0: frags a03+b01; issue L0..3(t+1)
#pragma unroll
    for (int mf = 0; mf < 4; mf++) {
      a[mf][0] = *reinterpret_cast<const bf16x8*>(pA + aof0 + mf * 2048);
      a[mf][1] = *reinterpret_cast<const bf16x8*>(pA + aof1 + mf * 2048);
    }
#pragma unroll
    for (int nf = 0; nf < 2; nf++) {
      b[nf][0] = *reinterpret_cast<const bf16x8*>(pB + boff[nf][0]);
      b[nf][1] = *reinterpret_cast<const bf16x8*>(pB + boff[nf][1]);
    }
    if (t + 1 < KT) {
      const float* g = gWb + (size_t)(t + 1) * 64 * NN;
      L0 = *reinterpret_cast<const float4*>(g);
      L1 = *reinterpret_cast<const float4*>(g + (size_t)1 * NN);
      L2 = *reinterpret_cast<const float4*>(g + (size_t)2 * NN);
      L3 = *reinterpret_cast<const float4*>(g + (size_t)3 * NN);
    }
    LGKM0_BAR();
    MFMA_QUAD(0, 0);
    __builtin_amdgcn_s_barrier();

    // ---------------- phase 1: frags b23; issue L4..7(t+1)
#pragma unroll
    for (int nf = 0; nf < 2; nf++) {
      b[2 + nf][0] = *reinterpret_cast<const bf16x8*>(pB + boff[2 + nf][0]);
      b[2 + nf][1] = *reinterpret_cast<const bf16x8*>(pB + boff[2 + nf][1]);
    }
    if (t + 1 < KT) {
      const float* g = gWb + (size_t)(t + 1) * 64 * NN;
      L4 = *reinterpret_cast<const float4*>(g + (size_t)4 * NN);
      L5 = *reinterpret_cast<const float4*>(g + (size_t)5 * NN);
      L6 = *reinterpret_cast<const float4*>(g + (size_t)6 * NN);
      L7 = *reinterpret_cast<const float4*>(g + (size_t)7 * NN);
    }
    LGKM0_BAR();
    MFMA_QUAD(0, 1);
    __builtin_amdgcn_s_barrier();

    // ---------------- phase 2: frags a47 (all A-reads of tile t done here)
#pragma unroll
    for (int mf = 0; mf < 4; mf++) {
      a[mf][0] = *reinterpret_cast<const bf16x8*>(pA + aof0 + (4 + mf) * 2048);
      a[mf][1] = *reinterpret_cast<const bf16x8*>(pA + aof1 + (4 + mf) * 2048);
    }
    LGKM0_BAR();
    MFMA_QUAD(1, 0);
    __builtin_amdgcn_s_barrier();

    // ---------------- phase 3: A(t+2) DMA; counted vmcnt; uint4 B-writes
    if (t + 2 < KT) { STAGE_HALF_A(t + 2, 0); STAGE_HALF_A(t + 2, 1); }
    if (t + 1 < KT) {
      if (t + 2 < KT)
        asm volatile("s_waitcnt vmcnt(4)" ::: "memory");  // L0..7 retired; ADMA in flight
      else
        asm volatile("s_waitcnt vmcnt(0)" ::: "memory");  // tail
      __builtin_amdgcn_sched_barrier(0);
#pragma unroll
      for (int i = 0; i < 4; i++) {
        uint4 v;
        v.x = pkbf(L0[i], L1[i]); v.y = pkbf(L2[i], L3[i]);
        v.z = pkbf(L4[i], L5[i]); v.w = pkbf(L6[i], L7[i]);
        *reinterpret_cast<uint4*>(wB + wbo[i]) = v;
      }
    }
    LGKM0_BAR();
    MFMA_QUAD(1, 1);
    __builtin_amdgcn_s_barrier();
  }
#undef STAGE_HALF_A
#undef MFMA_QUAD
#undef LGKM0_BAR

  // epilogue: D row = lhi*4+reg, col = l15 (verified C/D layout); bf16 out
#pragma unroll
  for (int mf = 0; mf < 8; mf++) {
#pragma unroll
    for (int nf = 0; nf < 4; nf++) {
#pragma unroll
      for (int rg = 0; rg < 4; rg++) {
        float v = acc[mf][nf][rg];
        int grow = mt * 256 + wm * 128 + mf * 16 + lhi * 4 + rg;
        int gcol = nt * 256 + wn * 64 + nf * 16 + l15;
        size_t off = ((size_t)e * CAP + grow) * NN + gcol;
        if constexpr (SILU) v = v / (1.0f + __expf(-v));  // silu
        Cout[off] = f2bf(v);
      }
    }
  }
}

// ------------------------------------------- weighted combine (no atomics)
__global__ void k_combine(const u16* __restrict__ yws, const int* __restrict__ slot_pos,
                          const float* __restrict__ w, float* __restrict__ out) {
  int tk = blockIdx.x;
  int t = threadIdx.x;  // 256 threads, 2 elems each
  int p0 = slot_pos[2 * tk], p1 = slot_pos[2 * tk + 1];
  float w0 = w[2 * tk], w1 = w[2 * tk + 1];
  unsigned ua = reinterpret_cast<const unsigned*>(yws + (size_t)p0 * HID)[t];
  unsigned ub = reinterpret_cast<const unsigned*>(yws + (size_t)p1 * HID)[t];
  float2 o;
  o.x = w0 * bf2f(ua & 0xffffu) + w1 * bf2f(ub & 0xffffu);
  o.y = w0 * bf2f(ua >> 16) + w1 * bf2f(ub >> 16);
  reinterpret_cast<float2*>(out + (size_t)tk * HID)[t] = o;
}

// ---------------------------------------------------------------- launcher
extern "C" void kernel_launch(void* const* d_in, const int* in_sizes, int n_in,
                              void* d_out, int out_size, void* d_ws, size_t ws_size,
                              hipStream_t stream) {
  const float* hs = (const float*)d_in[0];
  const float* wts = (const float*)d_in[1];
  const int* ids = (const int*)d_in[2];
  const float* W1 = (const float*)d_in[3];
  const float* W2 = (const float*)d_in[4];
  float* out = (float*)d_out;

  char* ws = (char*)d_ws;
  size_t o = 0;
  int* cnt = (int*)(ws + o);       o += 1024;
  int* slot_pos = (int*)(ws + o);  o += (size_t)NASSIGN * 4;
  int* tok_of = (int*)(ws + o);    o += (size_t)NASSIGN * 4;
  o = (o + 255) & ~(size_t)255;
  u16* Xg = (u16*)(ws + o);        o += (size_t)NASSIGN * HID * 2;      // 32 MB
  u16* hid = (u16*)(ws + o);       o += (size_t)NASSIGN * FFN * 2;      // 64 MB
  u16* yws = (u16*)(ws + o);       o += (size_t)NASSIGN * HID * 2;      // 32 MB

  hipMemsetAsync(cnt, 0, NEXP * sizeof(int), stream);
  k_route<<<(NASSIGN + 255) / 256, 256, 0, stream>>>(ids, cnt, tok_of, slot_pos);
  k_gather<<<NASSIGN / 4, 256, 0, stream>>>(hs, tok_of, Xg);
  k_gemm<HID, FFN, true><<<NEXP * (CAP / 256) * (FFN / 256), 512, 0, stream>>>(Xg, W1, hid);
  k_gemm<FFN, HID, false><<<NEXP * (CAP / 256) * (HID / 256), 512, 0, stream>>>(hid, W2, yws);
  k_combine<<<B_TOK, 256, 0, stream>>>(yws, slot_pos, wts, out);
}